// Round 4
// baseline (316.075 us; speedup 1.0000x reference)
//
#include <hip/hip_runtime.h>
#include <stdint.h>

#define PP 196            // 14*14
#define BP 6272           // 32*196

typedef _Float16 half_t;
typedef half_t half8v __attribute__((ext_vector_type(8)));
typedef half_t half4v __attribute__((ext_vector_type(4)));

// ---------------------------------------------------------------------------
// assign kernels: nearest-centroid 4-bit indices, packed 8 per u32, f64 math
// (reproduces the np reference's f32 argmin decisions except at f64-level ties).
// Centroids read DIRECTLY from global with wave-uniform indices -> s_load
// (scalar pipe), NOT via LDS: R2's per-fma LDS broadcasts were ~17-38 us/kernel.
// dist_k = sum_d c*(c - 2x) = c2 - 2*dot (exact f64-scaled ordering).
// idx layout: idxp[cb/8][BP]
// ---------------------------------------------------------------------------

template <typename T>
__global__ __launch_bounds__(256) void assign_1x1(
    const T* __restrict__ in, const float* __restrict__ cents,
    uint32_t* __restrict__ idxp, int nchan) {
  const int chunk = blockIdx.y;
  const int t = threadIdx.x;
  const int p = blockIdx.x * 256 + t;
  if (p >= BP) return;
  const unsigned b = (unsigned)p / 196u;
  const unsigned pr = (unsigned)p - b * 196u;
  const T* xb = in + ((size_t)b * nchan + chunk * 32) * PP + pr;
  double xv2[32];
#pragma unroll
  for (int i = 0; i < 32; i++) xv2[i] = 2.0 * (double)xb[(size_t)i * PP];
  uint32_t word = 0;
#pragma unroll 1
  for (int cb_l = 0; cb_l < 8; cb_l++) {
    const float* cw = cents + ((size_t)(chunk * 8 + cb_l)) * 64;  // uniform -> s_load
    double best = 1e300; int bi = 0;
#pragma unroll
    for (int k = 0; k < 16; k++) {
      double dist = 0.0;
#pragma unroll
      for (int d = 0; d < 4; d++) {
        double c = (double)cw[k * 4 + d];
        dist = fma(c, c - xv2[cb_l * 4 + d], dist);
      }
      if (dist < best) { best = dist; bi = k; }   // strict <: first-min
    }
    word |= (uint32_t)bi << (4 * cb_l);
  }
  idxp[(size_t)chunk * BP + p] = word;
}

__global__ __launch_bounds__(256) void assign_3x3(
    const double* __restrict__ in, const float* __restrict__ cents,
    uint32_t* __restrict__ idxp) {
  const int chunk = blockIdx.y;
  const int c0 = chunk * 8;
  const int t = threadIdx.x;
  const int p = blockIdx.x * 256 + t;
  if (p >= BP) return;
  const unsigned b = (unsigned)p / 196u;
  const unsigned pr = (unsigned)p - b * 196u;
  const int oh = pr / 14, ow = pr - oh * 14;
  uint32_t word = 0;
#pragma unroll 1
  for (int cb_l = 0; cb_l < 8; cb_l++) {
    const double* base = in + ((size_t)b * 256 + (c0 + cb_l)) * PP;
    double v2[9];
#pragma unroll
    for (int i = 0; i < 3; i++) {
#pragma unroll
      for (int j = 0; j < 3; j++) {
        int hh = oh + i - 1, ww = ow + j - 1;
        bool ok = (hh >= 0) & (hh < 14) & (ww >= 0) & (ww < 14);
        v2[i * 3 + j] = ok ? 2.0 * base[hh * 14 + ww] : 0.0;
      }
    }
    const float* cw = cents + ((size_t)(c0 + cb_l)) * 144;  // uniform -> s_load
    double best = 1e300; int bi = 0;
#pragma unroll
    for (int k = 0; k < 16; k++) {
      double dist = 0.0;
#pragma unroll
      for (int d = 0; d < 9; d++) {
        double c = (double)cw[k * 9 + d];
        dist = fma(c, c - v2[d], dist);
      }
      if (dist < best) { best = dist; bi = k; }
    }
    word |= (uint32_t)bi << (4 * cb_l);
  }
  idxp[(size_t)chunk * BP + p] = word;
}

// ---------------------------------------------------------------------------
// accum (f64): out[b][o][p] = act( scale[o]*sum_cb lut[cb][idx][o] + bias[o] (+res) )
// R2-proven two-barrier structure; LDS chunk [16 cb][16 k][16 ch] with k-stride
// padded to 36 floats -> 16B-aligned ds_read_b128 gathers, <=2-way banking (free).
// Added: register prefetch of next chunk's staging data + idx words, so the
// per-chunk global-load latency is hidden behind the gather phase.
// grid (49, NOUT/16), block 512: 128 positions x 16 out channels.
// ---------------------------------------------------------------------------
template <int NCB, int NOUT, bool RELU, bool RES, typename OutT>
__global__ __launch_bounds__(512) void accum_f64(
    const float* __restrict__ lut, const uint32_t* __restrict__ idxp,
    const float* __restrict__ scale, const float* __restrict__ bias,
    const float* __restrict__ res, OutT* __restrict__ out) {
  __shared__ float s_lut[16 * 16 * 36];  // 36 KB
  const int t = threadIdx.x;
  const int lane = t & 63;
  const int wave = t >> 6;
  const int q = wave & 3;          // output quad (4 channels)
  const int pg = wave >> 2;        // 0..1
  const int p = blockIdx.x * 128 + pg * 64 + lane;
  const int o_base = blockIdx.y * 16;
  const int r = t >> 1, h = t & 1;          // staging: row r=(cb,k), half h
  const int cb_ls = r >> 4, ks = r & 15;
  const float* src = lut + (((size_t)cb_ls) * 16 + ks) * NOUT + o_base + h * 8;
  const size_t cs = (size_t)256 * NOUT;     // 16 cb * 16 k per chunk
  constexpr int NCHUNK = NCB / 16;

  float4 va = *(const float4*)src;
  float4 vb = *(const float4*)(src + 4);
  uint32_t w0 = idxp[p];
  uint32_t w1 = idxp[(size_t)BP + p];
  double a0 = 0, a1 = 0, a2 = 0, a3 = 0;
  for (int ch = 0; ch < NCHUNK; ch++) {
    __syncthreads();               // prior chunk's gathers done
    {
      float* sd = s_lut + cb_ls * 576 + ks * 36 + h * 8;
      *(float4*)sd = va;
      *(float4*)(sd + 4) = vb;
    }
    __syncthreads();               // chunk published
    if (ch + 1 < NCHUNK) {
      const float* s2 = src + (size_t)(ch + 1) * cs;
      va = *(const float4*)s2;
      vb = *(const float4*)(s2 + 4);
    }
    uint32_t nw0 = 0, nw1 = 0;
    if (ch + 1 < NCHUNK) {
      nw0 = idxp[(size_t)(2 * ch + 2) * BP + p];
      nw1 = idxp[(size_t)(2 * ch + 3) * BP + p];
    }
#pragma unroll
    for (int cb_l = 0; cb_l < 16; cb_l++) {
      uint32_t w = (cb_l < 8) ? w0 : w1;
      int idx = (int)((w >> (4 * (cb_l & 7))) & 15u);
      const float4 v = *(const float4*)(s_lut + cb_l * 576 + idx * 36 + q * 4);
      a0 += (double)v.x; a1 += (double)v.y; a2 += (double)v.z; a3 += (double)v.w;
    }
    w0 = nw0; w1 = nw1;
  }
  const unsigned b = (unsigned)p / 196u;
  const unsigned pr = (unsigned)p - b * 196u;
  const int o = o_base + q * 4;
  const float4 sc = *(const float4*)(scale + o);
  const float4 bs = *(const float4*)(bias + o);
  double r0 = a0 * (double)sc.x + (double)bs.x;
  double r1 = a1 * (double)sc.y + (double)bs.y;
  double r2 = a2 * (double)sc.z + (double)bs.z;
  double r3 = a3 * (double)sc.w + (double)bs.w;
  if (RES) {
    const float* rp = res + ((size_t)b * NOUT + o) * PP + pr;
    r0 += (double)rp[0 * PP]; r1 += (double)rp[1 * PP];
    r2 += (double)rp[2 * PP]; r3 += (double)rp[3 * PP];
  }
  if (RELU) {
    r0 = fmax(r0, 0.0); r1 = fmax(r1, 0.0);
    r2 = fmax(r2, 0.0); r3 = fmax(r3, 0.0);
  }
  OutT* op = out + ((size_t)b * NOUT + o) * PP + pr;
  op[0 * PP] = (OutT)r0; op[1 * PP] = (OutT)r1;
  op[2 * PP] = (OutT)r2; op[3 * PP] = (OutT)r3;
}

// ---------------------------------------------------------------------------
// accum3 (f16 LUT, f32 accumulate): final layer only (no downstream argmin).
// One b128 gather = 8 channels -> half the gather instructions of the f32 path.
// LDS per cb: 16 k x 40 halfs (80 B rows = 5x16B): bank-quad = (5*idx+h)%8,
// distinct over idx mod 8, idx/idx+8 2-way (free). Two-barrier staging.
// grid (49, 64), block 256 (4 waves): 128 positions x 16 channels.
// ---------------------------------------------------------------------------
__global__ __launch_bounds__(256) void accum3_f16(
    const half_t* __restrict__ lut16, const uint32_t* __restrict__ idxp,
    const float* __restrict__ scale, const float* __restrict__ bias,
    const float* __restrict__ res, float* __restrict__ out) {
  __shared__ half_t s16[16 * 640];   // 20 KB
  const int t = threadIdx.x;
  const int lane = t & 63;
  const int wave = t >> 6;           // 0..3
  const int h = wave & 1;            // channel half (8 f16 ch)
  const int pg = wave >> 1;          // 0..1
  const int p = blockIdx.x * 128 + pg * 64 + lane;
  const int o_base = blockIdx.y * 16;
  // staging: slots s = t and t+256; s -> (cb = s>>5, k = (s>>1)&15, hh = s&1)
  const int s0cb = t >> 5, s0k = (t >> 1) & 15, s0h = t & 1;
  const int s1 = t + 256;
  const int s1cb = s1 >> 5, s1k = (s1 >> 1) & 15, s1h = s1 & 1;
  const half_t* srcA = lut16 + (((size_t)s0cb) * 16 + s0k) * 1024 + o_base + s0h * 8;
  const half_t* srcB = lut16 + (((size_t)s1cb) * 16 + s1k) * 1024 + o_base + s1h * 8;
  const size_t cs = (size_t)16 * 16 * 1024;   // 16 cb per chunk
  constexpr int NCHUNK = 4;

  half8v va = *(const half8v*)srcA;
  half8v vb = *(const half8v*)srcB;
  uint32_t w0 = idxp[p];
  uint32_t w1 = idxp[(size_t)BP + p];
  float a[8];
#pragma unroll
  for (int i = 0; i < 8; i++) a[i] = 0.f;
  for (int ch = 0; ch < NCHUNK; ch++) {
    __syncthreads();
    *(half8v*)(s16 + s0cb * 640 + s0k * 40 + s0h * 8) = va;
    *(half8v*)(s16 + s1cb * 640 + s1k * 40 + s1h * 8) = vb;
    __syncthreads();
    if (ch + 1 < NCHUNK) {
      va = *(const half8v*)(srcA + (size_t)(ch + 1) * cs);
      vb = *(const half8v*)(srcB + (size_t)(ch + 1) * cs);
    }
    uint32_t nw0 = 0, nw1 = 0;
    if (ch + 1 < NCHUNK) {
      nw0 = idxp[(size_t)(2 * ch + 2) * BP + p];
      nw1 = idxp[(size_t)(2 * ch + 3) * BP + p];
    }
#pragma unroll
    for (int cb_l = 0; cb_l < 16; cb_l++) {
      uint32_t w = (cb_l < 8) ? w0 : w1;
      int idx = (int)((w >> (4 * (cb_l & 7))) & 15u);
      const half8v v = *(const half8v*)(s16 + cb_l * 640 + idx * 40 + h * 8);
#pragma unroll
      for (int i = 0; i < 8; i++) a[i] += (float)v[i];
    }
    w0 = nw0; w1 = nw1;
  }
  const unsigned b = (unsigned)p / 196u;
  const unsigned pr = (unsigned)p - b * 196u;
  const int o = o_base + h * 8;
  const float* rp = res + ((size_t)b * 1024 + o) * PP + pr;
  float* op = out + ((size_t)b * 1024 + o) * PP + pr;
#pragma unroll
  for (int i = 0; i < 8; i++) {
    float v = a[i] * scale[o + i] + bias[o + i] + rp[(size_t)i * PP];
    op[(size_t)i * PP] = fmaxf(v, 0.f);
  }
}

// f32 -> f16 LUT conversion (1,048,576 elements)
__global__ __launch_bounds__(256) void cvt_f16(
    const float* __restrict__ src, half_t* __restrict__ dst, int n) {
  int i = (blockIdx.x * 256 + threadIdx.x) * 4;
  if (i < n) {
    float4 v = *(const float4*)(src + i);
    half4v o;
    o[0] = (half_t)v.x; o[1] = (half_t)v.y; o[2] = (half_t)v.z; o[3] = (half_t)v.w;
    *(half4v*)(dst + i) = o;
  }
}

// ---------------------------------------------------------------------------

extern "C" void kernel_launch(void* const* d_in, const int* in_sizes, int n_in,
                              void* d_out, int out_size, void* d_ws, size_t ws_size,
                              hipStream_t stream) {
  const float* x   = (const float*)d_in[0];   // [32,1024,14,14]
  const float* c1c = (const float*)d_in[1];
  const float* c1l = (const float*)d_in[2];
  const float* c1s = (const float*)d_in[3];
  const float* c1b = (const float*)d_in[4];
  const float* c2c = (const float*)d_in[5];
  const float* c2l = (const float*)d_in[6];
  const float* c2s = (const float*)d_in[7];
  const float* c2b = (const float*)d_in[8];
  const float* c3c = (const float*)d_in[9];
  const float* c3l = (const float*)d_in[10];  // [64,16,1024]
  const float* c3s = (const float*)d_in[11];
  const float* c3b = (const float*)d_in[12];

  const size_t sz_i1 = (size_t)32 * BP * 4;
  const size_t sz_i2 = (size_t)32 * BP * 4;
  const size_t sz_i3 = (size_t)8 * BP * 4;
  const size_t sz_l16 = (size_t)64 * 16 * 1024 * 2;   // 2 MB
  const size_t sz_o64 = (size_t)BP * 256 * 8;          // 12.85 MB

  char* w = (char*)d_ws;
  uint32_t* i1 = (uint32_t*)w; w += sz_i1;
  uint32_t* i2 = (uint32_t*)w; w += sz_i2;
  uint32_t* i3 = (uint32_t*)w; w += sz_i3;
  const size_t base_need = sz_i1 + sz_i2 + sz_i3;
  bool use_f16 = (ws_size >= base_need + sz_l16);
  half_t* l16 = (half_t*)w;
  if (use_f16) w += sz_l16;
  double *out1, *out2;
  if (ws_size >= (size_t)(w - (char*)d_ws) + 2 * sz_o64) {
    out1 = (double*)w;
    out2 = (double*)(w + sz_o64);
  } else {
    // d_out (25.69 MB f32) == exactly two 12.85 MB f64 arrays; the final
    // accum3 reads only i3/x/lut, then overwrites all of d_out.
    out1 = (double*)d_out;
    out2 = out1 + (size_t)BP * 256;
  }

  const dim3 blkA(256);
  if (use_f16)
    cvt_f16<<<dim3(1024), blkA, 0, stream>>>(c3l, l16, 64 * 16 * 1024);
  // layer 1: 1x1, 256 codebooks (dsub=4) over 1024 input channels
  assign_1x1<float><<<dim3(25, 32), blkA, 0, stream>>>(x, c1c, i1, 1024);
  accum_f64<256, 256, true, false, double><<<dim3(49, 16), dim3(512), 0, stream>>>(
      c1l, i1, c1s, c1b, nullptr, out1);
  // layer 2: 3x3, 256 codebooks (dsub=9)
  assign_3x3<<<dim3(25, 32), blkA, 0, stream>>>(out1, c2c, i2);
  accum_f64<256, 256, true, false, double><<<dim3(49, 16), dim3(512), 0, stream>>>(
      c2l, i2, c2s, c2b, nullptr, out2);
  // layer 3: 1x1, 64 codebooks over 256 channels; fused residual + relu
  assign_1x1<double><<<dim3(25, 8), blkA, 0, stream>>>(out2, c3c, i3, 256);
  if (use_f16)
    accum3_f16<<<dim3(49, 64), blkA, 0, stream>>>(
        l16, i3, c3s, c3b, x, (float*)d_out);
  else
    accum_f64<64, 1024, true, true, float><<<dim3(49, 64), dim3(512), 0, stream>>>(
        c3l, i3, c3s, c3b, x, (float*)d_out);
}